// Round 1
// baseline (1312.480 us; speedup 1.0000x reference)
//
#include <hip/hip_runtime.h>

// ChildHAggregation: B=32768 rows, HALF=512, DIM=1024.
// Algebraic restructure: attention (2x2) + LayerNorm folded into per-row scalars;
// all GEMMs run on raw inputs with bf16 MFMA (16x16x32), f32 accumulate.

typedef __attribute__((ext_vector_type(4))) float floatx4;
typedef __attribute__((ext_vector_type(8))) short shortx8;

#define NROWS 32768
#define MT 32          // rows per block
#define NT 64          // d-tile (output channel tile)
#define BK 32          // K staging chunk (= MFMA K)
#define APAD 40        // BK + 8 pad (bank-conflict break)
#define WMAT 262144    // 512*512 elements per transposed weight matrix

__device__ __forceinline__ unsigned short f2bf(float f){
  union { float f; unsigned u; } v; v.f = f;
  return (unsigned short)((v.u + 0x7fffu + ((v.u >> 16) & 1u)) >> 16);  // RNE
}

// ---------------- weight transpose + bf16 cast -------------------------------
// wt[t][n][k] = scale_k * src[t][(off+k)][n], 14 matrices of 512x512 (bf16, K-contig)
struct TrArgs {
  const float* src[14];
  int off[14];
  int sc[14];
};

__global__ __launch_bounds__(256) void ktr(TrArgs ta, const float* __restrict__ alpha,
                                           unsigned short* __restrict__ wt){
  __shared__ float tile[32][33];
  const int t  = blockIdx.x >> 8;
  const int ti = blockIdx.x & 255;
  const int n0 = (ti & 15) * 32, k0 = (ti >> 4) * 32;
  const float* src = ta.src[t];
  const int off = ta.off[t], sc = ta.sc[t];
  const int r = threadIdx.x >> 5, c = threadIdx.x & 31;
#pragma unroll
  for (int p = 0; p < 4; p++){
    const int kr = p*8 + r;
    float v = src[(size_t)(off + k0 + kr)*512 + n0 + c];
    if (sc) v *= alpha[off + k0 + kr];
    tile[kr][c] = v;
  }
  __syncthreads();
#pragma unroll
  for (int p = 0; p < 4; p++){
    const int nr = p*8 + r;
    wt[(size_t)t*WMAT + (size_t)(n0+nr)*512 + k0 + c] = f2bf(tile[c][nr]);
  }
}

// ---------------- s'[n] = sum_k alpha_k hU[k][n]; t'[n] = sum_k beta_k hU[k][n]
__global__ __launch_bounds__(256) void kst(const float* __restrict__ alpha, const float* __restrict__ beta,
                                           const float* __restrict__ hU,
                                           float* __restrict__ sp, float* __restrict__ tp){
  const int n = blockIdx.x*256 + threadIdx.x;
  float s = 0.f, t = 0.f;
  for (int k = 0; k < 1024; k++){
    const float wv = hU[(size_t)k*512 + n];
    s += alpha[k]*wv; t += beta[k]*wv;
  }
  sp[n] = s; tp[n] = t;
}

// ---------------- per-row stats: sum(hl), sum(hr), sum(hl^2), sum(hr^2), sum(hl*hr)
__global__ __launch_bounds__(256) void kstats(const float* __restrict__ hl, const float* __restrict__ hr,
                                              float* __restrict__ stats){
  const int w = threadIdx.x >> 6, lane = threadIdx.x & 63;
  const int row = blockIdx.x*4 + w;
  const float4* A  = (const float4*)(hl + (size_t)row*512);
  const float4* Bv = (const float4*)(hr + (size_t)row*512);
  float s1=0,s2=0,q1=0,q2=0,xc=0;
#pragma unroll
  for (int j=0;j<2;j++){
    const float4 a = A[lane + 64*j];
    const float4 b = Bv[lane + 64*j];
    s1 += a.x+a.y+a.z+a.w;
    s2 += b.x+b.y+b.z+b.w;
    q1 += a.x*a.x + a.y*a.y + a.z*a.z + a.w*a.w;
    q2 += b.x*b.x + b.y*b.y + b.z*b.z + b.w*b.w;
    xc += a.x*b.x + a.y*b.y + a.z*b.z + a.w*b.w;
  }
  for (int off=32; off; off>>=1){
    s1 += __shfl_down(s1,off); s2 += __shfl_down(s2,off);
    q1 += __shfl_down(q1,off); q2 += __shfl_down(q2,off);
    xc += __shfl_down(xc,off);
  }
  if (lane == 0){
    float* st = stats + (size_t)row*8;
    st[0]=s1; st[1]=s2; st[2]=q1; st[3]=q2; st[4]=xc;
  }
}

// ---------------- K1: 8 projections -> scores -> softmax + LN scalars --------
// proj p: 0:hl@qU 1:hr@qU 2:hl@kU 3:hr@kU 4:xh@qWu 5:xh@qWb 6:xh@kWu 7:xh@kWb
struct K1LDS {
  union alignas(16) {
    unsigned short stage[3*1280 + 6*2560];  // A tiles (32xAPAD) + B tiles (64xAPAD)
    float proj[8*2112];                     // 8 x 32 rows x 66 (padded 64)
  } u;
  float sred[32*8*4];
};

__global__ __launch_bounds__(256,2) void k1(
    const float* __restrict__ hl, const float* __restrict__ hr, const float* __restrict__ xh,
    const unsigned short* __restrict__ wt,
    const float* __restrict__ qUb, const float* __restrict__ qWub, const float* __restrict__ qWbb,
    const float* __restrict__ kUb, const float* __restrict__ kWub, const float* __restrict__ kWbb,
    const float* __restrict__ stats, float* __restrict__ scal)
{
  __shared__ K1LDS sm;
  const int tid = threadIdx.x, w = tid >> 6, lane = tid & 63;
  const int row0 = blockIdx.x * MT;
  unsigned short* stA = sm.u.stage;
  unsigned short* stB = sm.u.stage + 3*1280;
  floatx4 acc[4][4];
  floatx4 zf; zf[0]=0.f; zf[1]=0.f; zf[2]=0.f; zf[3]=0.f;
  float s0=0.f, s1=0.f, s2=0.f, s3=0.f;
  const int erow = tid >> 3, esub = tid & 7;

  for (int dt = 0; dt < 8; dt++){
    const int d0 = dt * NT;
#pragma unroll
    for (int i=0;i<4;i++)
#pragma unroll
      for (int ns=0;ns<4;ns++) acc[i][ns] = zf;

    for (int cch = 0; cch < 16; cch++){
      const int k0 = cch * BK;
      // stage A: hl,hr,xh (32 rows x 32 k each), f32 -> bf16
#pragma unroll
      for (int q0 = 0; q0 < 3; q0++){
        const int q = q0*256 + tid;
        const int a = q >> 8, rem = q & 255, r = rem >> 3, c4 = rem & 7;
        const float* src = (a==0) ? hl : ((a==1) ? hr : xh);
        const float4 v = *(const float4*)(src + (size_t)(row0 + r)*512 + k0 + c4*4);
        unsigned long long pk = (unsigned long long)f2bf(v.x)
                              | ((unsigned long long)f2bf(v.y) << 16)
                              | ((unsigned long long)f2bf(v.z) << 32)
                              | ((unsigned long long)f2bf(v.w) << 48);
        *(unsigned long long*)(stA + a*1280 + r*APAD + c4*4) = pk;
      }
      // stage B: 6 transposed weight tiles (64 n x 32 k), already bf16
#pragma unroll
      for (int q0 = 0; q0 < 6; q0++){
        const int q = q0*256 + tid;
        const int m = q >> 8, rem = q & 255, r = rem >> 2, c8 = rem & 3;
        *(uint4*)(stB + m*2560 + r*APAD + c8*8) =
            *(const uint4*)(wt + (size_t)m*WMAT + (size_t)(d0 + r)*512 + k0 + c8*8);
      }
      __syncthreads();
      shortx8 bfr[4];
#pragma unroll
      for (int i=0;i<4;i++){
        const int p = (w*4 + i) >> 1, ms = i & 1;
        if ((i & 1) == 0){
          const int bidx = (p < 4) ? (p >> 1) : (p - 2);
#pragma unroll
          for (int ns=0;ns<4;ns++)
            bfr[ns] = *(const shortx8*)(stB + bidx*2560 + (ns*16 + (lane & 15))*APAD + (lane >> 4)*8);
        }
        const int aidx = (p < 4) ? (p & 1) : 2;
        const shortx8 af = *(const shortx8*)(stA + aidx*1280 + (ms*16 + (lane & 15))*APAD + (lane >> 4)*8);
#pragma unroll
        for (int ns=0;ns<4;ns++)
          acc[i][ns] = __builtin_amdgcn_mfma_f32_16x16x32_bf16(af, bfr[ns], acc[i][ns], 0, 0, 0);
      }
      __syncthreads();
    }
    // write projections to LDS (C layout: col=lane&15, row=(lane>>4)*4+r)
#pragma unroll
    for (int i=0;i<4;i++){
      const int p = (w*4 + i) >> 1, ms = i & 1;
#pragma unroll
      for (int ns=0;ns<4;ns++)
#pragma unroll
        for (int r=0;r<4;r++)
          sm.u.proj[p*2112 + (ms*16 + (lane >> 4)*4 + r)*66 + ns*16 + (lane & 15)] = acc[i][ns][r];
    }
    __syncthreads();
    // accumulate score partials (8 threads per row, 8 d each)
#pragma unroll
    for (int j=0;j<8;j++){
      const int dd = esub*8 + j, gd = d0 + dd;
      const float ul = sm.u.proj[0*2112 + erow*66 + dd];
      const float ur = sm.u.proj[1*2112 + erow*66 + dd];
      const float vl = sm.u.proj[2*2112 + erow*66 + dd];
      const float vr = sm.u.proj[3*2112 + erow*66 + dd];
      const float pm = sm.u.proj[4*2112 + erow*66 + dd];
      const float pn = sm.u.proj[5*2112 + erow*66 + dd];
      const float pm2= sm.u.proj[6*2112 + erow*66 + dd];
      const float pn2= sm.u.proj[7*2112 + erow*66 + dd];
      const float f1 = pm + qWub[gd], f2 = pn + qWbb[gd];
      const float g1 = pm2 + kWub[gd], g2 = pn2 + kWbb[gd];
      const float ub = qUb[gd], kb = kUb[gd];
      const float ql = (ul + ub)*f1 + f2;
      const float qr = (ur + ub)*f1 + f2;
      const float kl = (vl + kb)*g1 + g2;
      const float kr = (vr + kb)*g1 + g2;
      s0 += ql*kl; s1 += ql*kr; s2 += qr*kl; s3 += qr*kr;
    }
    __syncthreads();
  }
  // reduce 8 partials/row, softmax, LN scalars
  {
    float* sr = sm.sred + (erow*8 + esub)*4;
    sr[0]=s0; sr[1]=s1; sr[2]=s2; sr[3]=s3;
  }
  __syncthreads();
  if (tid < MT){
    const int row = tid;
    float t00=0,t01=0,t10=0,t11=0;
#pragma unroll
    for (int j=0;j<8;j++){
      const float* p = sm.sred + (row*8 + j)*4;
      t00+=p[0]; t01+=p[1]; t10+=p[2]; t11+=p[3];
    }
    const float isq = 0.044194173824159216f;  // 1/sqrt(512)
    t00*=isq; t01*=isq; t10*=isq; t11*=isq;
    const float m0 = fmaxf(t00,t01), m1 = fmaxf(t10,t11);
    const float e00 = expf(t00-m0), e01 = expf(t01-m0);
    const float e10 = expf(t10-m1), e11 = expf(t11-m1);
    const float p00 = e00/(e00+e01), p01 = e01/(e00+e01);
    const float p10 = e10/(e10+e11), p11 = e11/(e10+e11);
    const float* st = stats + (size_t)(row0+row)*8;
    const float S1=st[0], S2=st[1], Q1=st[2], Q2=st[3], Xc=st[4];
    const float a0=1.f+p00, a1=p01, b0=p10, b1=1.f+p11;
    const float mean = ((a0+b0)*S1 + (a1+b1)*S2) * (1.f/1024.f);
    const float ssq = (a0*a0+b0*b0)*Q1 + (a1*a1+b1*b1)*Q2 + 2.f*(a0*a1+b0*b1)*Xc;
    const float var = (ssq - 1024.f*mean*mean) * (1.f/1023.f);
    const float inv = 1.f/(sqrtf(fmaxf(var,0.f)) + 1e-6f);
    float* so = scal + (size_t)(row0+row)*8;
    so[0]=p00; so[1]=p01; so[2]=p10; so[3]=p11; so[4]=mean; so[5]=inv;
  }
}

// ---------------- K2: 9 projections -> epilogue combine -> out ---------------
// p: 0:hl@hU't 1:hr@hU't 2:hl@hU'b 3:hr@hU'b 4:xh@hWu 5:xh@hWb 6:xh@lWu 7:xh@lWb
//    8:xw_lo@lU_lo 9:xw_hi@lU_hi (summed into slot 8)
struct K2LDS {
  union alignas(16) {
    unsigned short stage[5*1280 + 8*2560];
    float proj[9*2112];
  } u;
};

__global__ __launch_bounds__(256,2) void k2(
    const float* __restrict__ hl, const float* __restrict__ hr,
    const float* __restrict__ xh, const float* __restrict__ xw,
    const unsigned short* __restrict__ wt,
    const float* __restrict__ sp, const float* __restrict__ tp,
    const float* __restrict__ hUb, const float* __restrict__ hWub, const float* __restrict__ hWbb,
    const float* __restrict__ lUb, const float* __restrict__ lWub, const float* __restrict__ lWbb,
    const float* __restrict__ scal, float* __restrict__ out)
{
  __shared__ K2LDS sm;
  const int tid = threadIdx.x, w = tid >> 6, lane = tid & 63;
  const int row0 = blockIdx.x * MT;
  unsigned short* stA = sm.u.stage;
  unsigned short* stB = sm.u.stage + 5*1280;
  const int erow = tid >> 3, ej0 = (tid & 7)*8;
  const float* sl = scal + (size_t)(row0 + erow)*8;
  const float p00 = sl[0], p01 = sl[1], p10 = sl[2], p11 = sl[3], mean = sl[4], inv = sl[5];
  const float a0 = 1.f + p00, a1 = p01, b0 = p10, b1 = 1.f + p11;
  floatx4 acc[5][4];
  floatx4 zf; zf[0]=0.f; zf[1]=0.f; zf[2]=0.f; zf[3]=0.f;

  for (int dt = 0; dt < 8; dt++){
    const int d0 = dt * NT;
#pragma unroll
    for (int i=0;i<5;i++)
#pragma unroll
      for (int ns=0;ns<4;ns++) acc[i][ns] = zf;

    for (int cch = 0; cch < 16; cch++){
      const int k0 = cch * BK;
      // stage A: hl, hr, xh, xw_lo, xw_hi
#pragma unroll
      for (int q0 = 0; q0 < 5; q0++){
        const int q = q0*256 + tid;
        const int a = q >> 8, rem = q & 255, r = rem >> 3, c4 = rem & 7;
        const float* srcb = (a==0) ? hl : ((a==1) ? hr : ((a==2) ? xh : xw));
        const int stride = (a >= 3) ? 1024 : 512;
        const int coff = (a == 4) ? 512 : 0;
        const float4 v = *(const float4*)(srcb + (size_t)(row0 + r)*stride + coff + k0 + c4*4);
        unsigned long long pk = (unsigned long long)f2bf(v.x)
                              | ((unsigned long long)f2bf(v.y) << 16)
                              | ((unsigned long long)f2bf(v.z) << 32)
                              | ((unsigned long long)f2bf(v.w) << 48);
        *(unsigned long long*)(stA + a*1280 + r*APAD + c4*4) = pk;
      }
      // stage B: wt[6..13]
#pragma unroll
      for (int q0 = 0; q0 < 8; q0++){
        const int q = q0*256 + tid;
        const int m = q >> 8, rem = q & 255, r = rem >> 2, c8 = rem & 3;
        *(uint4*)(stB + m*2560 + r*APAD + c8*8) =
            *(const uint4*)(wt + (size_t)(m+6)*WMAT + (size_t)(d0 + r)*512 + k0 + c8*8);
      }
      __syncthreads();
      shortx8 bfr[4];
      int prevB = -1;
#pragma unroll
      for (int i=0;i<5;i++){
        const int wtask = w*5 + i, p = wtask >> 1, ms = wtask & 1;
        const int bl = (p<4) ? (p>>1) : ((p<6) ? (p-2) : ((p<8) ? p : (p-4)));
        if (bl != prevB){
#pragma unroll
          for (int ns=0;ns<4;ns++)
            bfr[ns] = *(const shortx8*)(stB + bl*2560 + (ns*16 + (lane&15))*APAD + (lane>>4)*8);
          prevB = bl;
        }
        const int am = (p<4) ? (p&1) : ((p<8) ? 2 : (p-5));
        const shortx8 af = *(const shortx8*)(stA + am*1280 + (ms*16 + (lane&15))*APAD + (lane>>4)*8);
#pragma unroll
        for (int ns=0;ns<4;ns++)
          acc[i][ns] = __builtin_amdgcn_mfma_f32_16x16x32_bf16(af, bfr[ns], acc[i][ns], 0, 0, 0);
      }
      __syncthreads();
    }
    // write projections (p9 adds into slot 8; same lanes wrote p8 earlier -> safe)
#pragma unroll
    for (int i=0;i<5;i++){
      const int wtask = w*5 + i, p = wtask >> 1, ms = wtask & 1;
      const int slot = (p == 9) ? 8 : p;
#pragma unroll
      for (int ns=0;ns<4;ns++)
#pragma unroll
        for (int r=0;r<4;r++){
          float* dst = &sm.u.proj[slot*2112 + (ms*16 + (lane>>4)*4 + r)*66 + ns*16 + (lane & 15)];
          if (p == 9) *dst += acc[i][ns][r]; else *dst = acc[i][ns][r];
        }
    }
    __syncthreads();
    // combine + store
    float res[8];
#pragma unroll
    for (int j=0;j<8;j++){
      const int dd = ej0 + j, gd = d0 + dd;
      const float A1 = sm.u.proj[0*2112 + erow*66 + dd];
      const float A2 = sm.u.proj[1*2112 + erow*66 + dd];
      const float A3 = sm.u.proj[2*2112 + erow*66 + dd];
      const float A4 = sm.u.proj[3*2112 + erow*66 + dd];
      const float Hm = sm.u.proj[4*2112 + erow*66 + dd];
      const float Hb = sm.u.proj[5*2112 + erow*66 + dd];
      const float Lm = sm.u.proj[6*2112 + erow*66 + dd];
      const float Lb = sm.u.proj[7*2112 + erow*66 + dd];
      const float Lu = sm.u.proj[8*2112 + erow*66 + dd];
      const float attnU = a0*A1 + a1*A2 + b0*A3 + b1*A4;
      const float xlnU = inv*(attnU - mean*sp[gd]) + tp[gd] + hUb[gd];
      const float hid = xlnU*(Hm + hWub[gd]) + (Hb + hWbb[gd]);
      const float lf = (Lu + lUb[gd])*(Lm + lWub[gd]) + (Lb + lWbb[gd]);
      res[j] = hid + lf;
    }
    float4 r0; r0.x=res[0]; r0.y=res[1]; r0.z=res[2]; r0.w=res[3];
    float4 r1; r1.x=res[4]; r1.y=res[5]; r1.z=res[6]; r1.w=res[7];
    float4* op = (float4*)(out + (size_t)(row0+erow)*512 + d0 + ej0);
    op[0] = r0; op[1] = r1;
    __syncthreads();
  }
}

// ---------------- launch -----------------------------------------------------
extern "C" void kernel_launch(void* const* d_in, const int* in_sizes, int n_in,
                              void* d_out, int out_size, void* d_ws, size_t ws_size,
                              hipStream_t stream)
{
  const float* hl    = (const float*)d_in[0];
  const float* hr    = (const float*)d_in[1];
  const float* xw    = (const float*)d_in[2];
  const float* xh    = (const float*)d_in[3];
  const float* qU_w  = (const float*)d_in[4];
  const float* qU_b  = (const float*)d_in[5];
  const float* qWu_w = (const float*)d_in[6];
  const float* qWu_b = (const float*)d_in[7];
  const float* qWb_w = (const float*)d_in[8];
  const float* qWb_b = (const float*)d_in[9];
  const float* kU_w  = (const float*)d_in[10];
  const float* kU_b  = (const float*)d_in[11];
  const float* kWu_w = (const float*)d_in[12];
  const float* kWu_b = (const float*)d_in[13];
  const float* kWb_w = (const float*)d_in[14];
  const float* kWb_b = (const float*)d_in[15];
  const float* alpha = (const float*)d_in[16];
  const float* beta  = (const float*)d_in[17];
  const float* hU_w  = (const float*)d_in[18];
  const float* hU_b  = (const float*)d_in[19];
  const float* hWu_w = (const float*)d_in[20];
  const float* hWu_b = (const float*)d_in[21];
  const float* hWb_w = (const float*)d_in[22];
  const float* hWb_b = (const float*)d_in[23];
  const float* lU_w  = (const float*)d_in[24];
  const float* lU_b  = (const float*)d_in[25];
  const float* lWu_w = (const float*)d_in[26];
  const float* lWu_b = (const float*)d_in[27];
  const float* lWb_w = (const float*)d_in[28];
  const float* lWb_b = (const float*)d_in[29];

  char* ws = (char*)d_ws;
  unsigned short* wt = (unsigned short*)ws;     // 14*512*512 bf16 = 7,340,032 B
  float* sp    = (float*)(ws + 7340032);        // 512 f32
  float* tp    = sp + 512;                      // 512 f32
  float* stats = (float*)(ws + 7344128);        // 32768*8 f32
  float* scal  = (float*)(ws + 8392704);        // 32768*8 f32   (total ~9.4 MB)

  TrArgs ta;
  const float* wsrc[14] = {qU_w,kU_w,qWu_w,qWb_w,kWu_w,kWb_w,hU_w,hU_w,hWu_w,hWb_w,lU_w,lU_w,lWu_w,lWb_w};
  const int woff[14] = {0,0,0,0,0,0,0,512,0,0,0,512,0,0};
  const int wsc[14]  = {0,0,0,0,0,0,1,1,0,0,0,0,0,0};
  for (int i=0;i<14;i++){ ta.src[i]=wsrc[i]; ta.off[i]=woff[i]; ta.sc[i]=wsc[i]; }

  ktr   <<<dim3(14*256),  dim3(256), 0, stream>>>(ta, alpha, wt);
  kst   <<<dim3(2),       dim3(256), 0, stream>>>(alpha, beta, hU_w, sp, tp);
  kstats<<<dim3(NROWS/4), dim3(256), 0, stream>>>(hl, hr, stats);
  k1    <<<dim3(NROWS/MT),dim3(256), 0, stream>>>(hl, hr, xh, wt,
            qU_b, qWu_b, qWb_b, kU_b, kWu_b, kWb_b, stats, scal);
  k2    <<<dim3(NROWS/MT),dim3(256), 0, stream>>>(hl, hr, xh, xw, wt, sp, tp,
            hU_b, hWu_b, hWb_b, lU_b, lWu_b, lWb_b, scal, (float*)d_out);
}

// Round 2
// 1144.332 us; speedup vs baseline: 1.1469x; 1.1469x over previous
//
#include <hip/hip_runtime.h>

// ChildHAggregation: B=32768 rows, HALF=512, DIM=1024.
// R2: ns-partitioned waves (epilogues in-register), global_load_lds weight
// staging, bf16-preconverted activations in ws (f32 fallback if ws small).

typedef __attribute__((ext_vector_type(4))) float floatx4;
typedef __attribute__((ext_vector_type(8))) short shortx8;

#define NROWS 32768
#define WMAT 262144    // 512*512 elements per transposed weight matrix

#define MFMA16(a,b,c) __builtin_amdgcn_mfma_f32_16x16x32_bf16(a,b,c,0,0,0)

__device__ __forceinline__ unsigned short f2bf(float f){
  union { float f; unsigned u; } v; v.f = f;
  return (unsigned short)((v.u + 0x7fffu + ((v.u >> 16) & 1u)) >> 16);  // RNE
}

__device__ __forceinline__ unsigned long long pack4(float4 v){
  return (unsigned long long)f2bf(v.x) | ((unsigned long long)f2bf(v.y)<<16)
       | ((unsigned long long)f2bf(v.z)<<32) | ((unsigned long long)f2bf(v.w)<<48);
}

__device__ __forceinline__ void gl_lds16(const void* g, void* l){
  __builtin_amdgcn_global_load_lds(
      (const __attribute__((address_space(1))) unsigned int*)g,
      (__attribute__((address_space(3))) unsigned int*)l, 16, 0, 0);
}

// ---------------- weight transpose + bf16 cast (unchanged, verified R1) -----
struct TrArgs {
  const float* src[14];
  int off[14];
  int sc[14];
};

__global__ __launch_bounds__(256) void ktr(TrArgs ta, const float* __restrict__ alpha,
                                           unsigned short* __restrict__ wt){
  __shared__ float tile[32][33];
  const int t  = blockIdx.x >> 8;
  const int ti = blockIdx.x & 255;
  const int n0 = (ti & 15) * 32, k0 = (ti >> 4) * 32;
  const float* src = ta.src[t];
  const int off = ta.off[t], sc = ta.sc[t];
  const int r = threadIdx.x >> 5, c = threadIdx.x & 31;
#pragma unroll
  for (int p = 0; p < 4; p++){
    const int kr = p*8 + r;
    float v = src[(size_t)(off + k0 + kr)*512 + n0 + c];
    if (sc) v *= alpha[off + k0 + kr];
    tile[kr][c] = v;
  }
  __syncthreads();
#pragma unroll
  for (int p = 0; p < 4; p++){
    const int nr = p*8 + r;
    wt[(size_t)t*WMAT + (size_t)(n0+nr)*512 + k0 + c] = f2bf(tile[c][nr]);
  }
}

// ---------------- sp/tp columns (unchanged, verified R1) ---------------------
__global__ __launch_bounds__(256) void kst(const float* __restrict__ alpha, const float* __restrict__ beta,
                                           const float* __restrict__ hU,
                                           float* __restrict__ sp, float* __restrict__ tp){
  const int n = blockIdx.x*256 + threadIdx.x;
  float s = 0.f, t = 0.f;
  for (int k = 0; k < 1024; k++){
    const float wv = hU[(size_t)k*512 + n];
    s += alpha[k]*wv; t += beta[k]*wv;
  }
  sp[n] = s; tp[n] = t;
}

// ---------------- stats only (f32 fallback path) -----------------------------
__global__ __launch_bounds__(256) void kstats(const float* __restrict__ hl, const float* __restrict__ hr,
                                              float* __restrict__ stats){
  const int w = threadIdx.x >> 6, lane = threadIdx.x & 63;
  const int row = blockIdx.x*4 + w;
  const float4* A  = (const float4*)(hl + (size_t)row*512);
  const float4* Bv = (const float4*)(hr + (size_t)row*512);
  float s1=0,s2=0,q1=0,q2=0,xc=0;
#pragma unroll
  for (int j=0;j<2;j++){
    const float4 a = A[lane + 64*j];
    const float4 b = Bv[lane + 64*j];
    s1 += a.x+a.y+a.z+a.w;  s2 += b.x+b.y+b.z+b.w;
    q1 += a.x*a.x + a.y*a.y + a.z*a.z + a.w*a.w;
    q2 += b.x*b.x + b.y*b.y + b.z*b.z + b.w*b.w;
    xc += a.x*b.x + a.y*b.y + a.z*b.z + a.w*b.w;
  }
  for (int off=32; off; off>>=1){
    s1 += __shfl_down(s1,off); s2 += __shfl_down(s2,off);
    q1 += __shfl_down(q1,off); q2 += __shfl_down(q2,off);
    xc += __shfl_down(xc,off);
  }
  if (lane == 0){
    float* st = stats + (size_t)row*8;
    st[0]=s1; st[1]=s2; st[2]=q1; st[3]=q2; st[4]=xc;
  }
}

// ---------------- fused stats + hl/hr bf16 conversion ------------------------
__global__ __launch_bounds__(256) void kconv_stats(const float* __restrict__ hl, const float* __restrict__ hr,
                                                   unsigned short* __restrict__ hlb, unsigned short* __restrict__ hrb,
                                                   float* __restrict__ stats){
  const int w = threadIdx.x >> 6, lane = threadIdx.x & 63;
  const int row = blockIdx.x*4 + w;
  const float4* A  = (const float4*)(hl + (size_t)row*512);
  const float4* Bv = (const float4*)(hr + (size_t)row*512);
  float s1=0,s2=0,q1=0,q2=0,xc=0;
#pragma unroll
  for (int j=0;j<2;j++){
    const float4 a = A[lane + 64*j];
    const float4 b = Bv[lane + 64*j];
    s1 += a.x+a.y+a.z+a.w;  s2 += b.x+b.y+b.z+b.w;
    q1 += a.x*a.x + a.y*a.y + a.z*a.z + a.w*a.w;
    q2 += b.x*b.x + b.y*b.y + b.z*b.z + b.w*b.w;
    xc += a.x*b.x + a.y*b.y + a.z*b.z + a.w*b.w;
    *(unsigned long long*)(hlb + (size_t)row*512 + (lane + 64*j)*4) = pack4(a);
    *(unsigned long long*)(hrb + (size_t)row*512 + (lane + 64*j)*4) = pack4(b);
  }
  for (int off=32; off; off>>=1){
    s1 += __shfl_down(s1,off); s2 += __shfl_down(s2,off);
    q1 += __shfl_down(q1,off); q2 += __shfl_down(q2,off);
    xc += __shfl_down(xc,off);
  }
  if (lane == 0){
    float* st = stats + (size_t)row*8;
    st[0]=s1; st[1]=s2; st[2]=q1; st[3]=q2; st[4]=xc;
  }
}

// ---------------- xh/xw bf16 conversion --------------------------------------
__global__ __launch_bounds__(256) void kact(const float* __restrict__ xh, const float* __restrict__ xw,
                                            unsigned short* __restrict__ xhb, unsigned short* __restrict__ xwb){
  const int bid = blockIdx.x;
  const float* src; unsigned short* dst; size_t base;
  if (bid < 8192){ src = xh; dst = xhb; base = (size_t)bid*2048; }
  else           { src = xw; dst = xwb; base = (size_t)(bid-8192)*2048; }
  const size_t i = base + (size_t)threadIdx.x*8;
  const float4 v0 = *(const float4*)(src + i);
  const float4 v1 = *(const float4*)(src + i + 4);
  unsigned long long p0 = pack4(v0), p1 = pack4(v1);
  *(unsigned long long*)(dst + i)     = p0;
  *(unsigned long long*)(dst + i + 4) = p1;
}

// ---------------- K1: 8 projections -> scores -> softmax + LN scalars --------
// proj p: 0:hl@qU 1:hr@qU 2:hl@kU 3:hr@kU 4:xh@qWu 5:xh@qWb 6:xh@kWu 7:xh@kWb
// wt idx:      qU=0 kU=1 qWu=2 qWb=3 kWu=4 kWb=5
// NT=128 (4 d-tiles), wave w owns cols [w*32, w*32+32) of the tile (2 ns).
template<int PRE>
__global__ __launch_bounds__(256,2) void k1(
    const float* __restrict__ hl, const float* __restrict__ hr, const float* __restrict__ xh,
    const unsigned short* __restrict__ hlb, const unsigned short* __restrict__ hrb,
    const unsigned short* __restrict__ xhb,
    const unsigned short* __restrict__ wt,
    const float* __restrict__ qUb, const float* __restrict__ qWub, const float* __restrict__ qWbb,
    const float* __restrict__ kUb, const float* __restrict__ kWub, const float* __restrict__ kWbb,
    const float* __restrict__ stats, float* __restrict__ scal)
{
  __shared__ __align__(16) unsigned short Ash[3*1024];   // 3 tiles 32x32 bf16, k-contig
  __shared__ __align__(16) unsigned short Bsh[6*4096];   // 6 tiles 128x32 bf16, k-contig
  __shared__ float sred[512];                            // [wave][row][score]
  const int tid = threadIdx.x, w = tid >> 6, lane = tid & 63;
  const int cq = lane & 15, cr = lane >> 4;
  const int row0 = blockIdx.x * 32;

  for (int i = tid; i < 512; i += 256) sred[i] = 0.f;

  floatx4 acc[8][2][2];
  floatx4 zf; zf[0]=0.f; zf[1]=0.f; zf[2]=0.f; zf[3]=0.f;

#pragma unroll 1
  for (int dt = 0; dt < 4; dt++){
    const int d0 = dt * 128;
#pragma unroll
    for (int p=0;p<8;p++)
#pragma unroll
      for (int ms=0;ms<2;ms++){ acc[p][ms][0]=zf; acc[p][ms][1]=zf; }

#pragma unroll 1
    for (int cc = 0; cc < 16; cc++){
      const int k0 = cc * 32;
      if (PRE){
#pragma unroll
        for (int j=0;j<2;j++){
          const int idx = j*256 + tid;
          if (idx < 384){
            const int a = idx>>7, wi = idx&127, r = wi>>2, kg = wi&3;
            const unsigned short* s = (a==0) ? hlb : ((a==1) ? hrb : xhb);
            gl_lds16(s + (size_t)(row0+r)*512 + k0 + kg*8, Ash + idx*8);
          }
        }
      } else {
#pragma unroll
        for (int a=0;a<3;a++){
          const int r = tid>>3, c4 = tid&7;
          const float* s = (a==0) ? hl : ((a==1) ? hr : xh);
          const float4 v = *(const float4*)(s + (size_t)(row0+r)*512 + k0 + c4*4);
          *(unsigned long long*)(Ash + a*1024 + r*32 + c4*4) = pack4(v);
        }
      }
#pragma unroll
      for (int j=0;j<12;j++){
        const int idx = j*256 + tid;
        const int m = idx>>9, wi = idx&511, r = wi>>2, kg = wi&3;
        gl_lds16(wt + (size_t)m*WMAT + (size_t)(d0+r)*512 + k0 + kg*8, Bsh + idx*8);
      }
      __syncthreads();
      shortx8 af[3][2], bf[6];
#pragma unroll
      for (int a=0;a<3;a++)
#pragma unroll
        for (int ms=0;ms<2;ms++)
          af[a][ms] = *(const shortx8*)(Ash + a*1024 + (ms*16+cq)*32 + cr*8);
#pragma unroll
      for (int n=0;n<2;n++){
#pragma unroll
        for (int m=0;m<6;m++)
          bf[m] = *(const shortx8*)(Bsh + m*4096 + (w*32 + n*16 + cq)*32 + cr*8);
#pragma unroll
        for (int ms=0;ms<2;ms++){
          acc[0][ms][n] = MFMA16(af[0][ms], bf[0], acc[0][ms][n]);
          acc[1][ms][n] = MFMA16(af[1][ms], bf[0], acc[1][ms][n]);
          acc[2][ms][n] = MFMA16(af[0][ms], bf[1], acc[2][ms][n]);
          acc[3][ms][n] = MFMA16(af[1][ms], bf[1], acc[3][ms][n]);
          acc[4][ms][n] = MFMA16(af[2][ms], bf[2], acc[4][ms][n]);
          acc[5][ms][n] = MFMA16(af[2][ms], bf[3], acc[5][ms][n]);
          acc[6][ms][n] = MFMA16(af[2][ms], bf[4], acc[6][ms][n]);
          acc[7][ms][n] = MFMA16(af[2][ms], bf[5], acc[7][ms][n]);
        }
      }
      __syncthreads();
    }
    // --------- in-register epilogue: score partials for this d-tile ---------
    float qub[2], qwu[2], qwb[2], kub[2], kwu[2], kwb[2];
#pragma unroll
    for (int n=0;n<2;n++){
      const int col = d0 + w*32 + n*16 + cq;
      qub[n]=qUb[col]; qwu[n]=qWub[col]; qwb[n]=qWbb[col];
      kub[n]=kUb[col]; kwu[n]=kWub[col]; kwb[n]=kWbb[col];
    }
    float sc[2][4][4];
#pragma unroll
    for (int ms=0;ms<2;ms++)
#pragma unroll
      for (int r=0;r<4;r++){ sc[ms][r][0]=0.f; sc[ms][r][1]=0.f; sc[ms][r][2]=0.f; sc[ms][r][3]=0.f; }
#pragma unroll
    for (int ms=0;ms<2;ms++)
#pragma unroll
      for (int n=0;n<2;n++)
#pragma unroll
        for (int r=0;r<4;r++){
          const float ul = acc[0][ms][n][r], ur = acc[1][ms][n][r];
          const float vl = acc[2][ms][n][r], vr = acc[3][ms][n][r];
          const float f1 = acc[4][ms][n][r] + qwu[n], f2 = acc[5][ms][n][r] + qwb[n];
          const float g1 = acc[6][ms][n][r] + kwu[n], g2 = acc[7][ms][n][r] + kwb[n];
          const float ql = (ul + qub[n])*f1 + f2, qr = (ur + qub[n])*f1 + f2;
          const float kl = (vl + kub[n])*g1 + g2, kr = (vr + kub[n])*g1 + g2;
          sc[ms][r][0] += ql*kl; sc[ms][r][1] += ql*kr;
          sc[ms][r][2] += qr*kl; sc[ms][r][3] += qr*kr;
        }
#pragma unroll
    for (int b=1;b<16;b<<=1)
#pragma unroll
      for (int ms=0;ms<2;ms++)
#pragma unroll
        for (int r=0;r<4;r++)
#pragma unroll
          for (int c=0;c<4;c++)
            sc[ms][r][c] += __shfl_xor(sc[ms][r][c], b);
    if (cq == 0){
#pragma unroll
      for (int ms=0;ms<2;ms++)
#pragma unroll
        for (int r=0;r<4;r++){
          const int row = ms*16 + cr*4 + r;
#pragma unroll
          for (int c=0;c<4;c++)
            sred[w*128 + row*4 + c] += sc[ms][r][c];
        }
    }
  }
  __syncthreads();
  if (tid < 32){
    const int row = tid;
    float t00=0,t01=0,t10=0,t11=0;
#pragma unroll
    for (int w2=0;w2<4;w2++){
      const int base = w2*128 + row*4;
      t00+=sred[base+0]; t01+=sred[base+1]; t10+=sred[base+2]; t11+=sred[base+3];
    }
    const float isq = 0.044194173824159216f;  // 1/sqrt(512)
    t00*=isq; t01*=isq; t10*=isq; t11*=isq;
    const float m0 = fmaxf(t00,t01), m1 = fmaxf(t10,t11);
    const float e00 = expf(t00-m0), e01 = expf(t01-m0);
    const float e10 = expf(t10-m1), e11 = expf(t11-m1);
    const float p00 = e00/(e00+e01), p01 = e01/(e00+e01);
    const float p10 = e10/(e10+e11), p11 = e11/(e10+e11);
    const float* st = stats + (size_t)(row0+row)*8;
    const float S1=st[0], S2=st[1], Q1=st[2], Q2=st[3], Xc=st[4];
    const float a0=1.f+p00, a1=p01, b0=p10, b1=1.f+p11;
    const float mean = ((a0+b0)*S1 + (a1+b1)*S2) * (1.f/1024.f);
    const float ssq = (a0*a0+b0*b0)*Q1 + (a1*a1+b1*b1)*Q2 + 2.f*(a0*a1+b0*b1)*Xc;
    const float var = (ssq - 1024.f*mean*mean) * (1.f/1023.f);
    const float inv = 1.f/(sqrtf(fmaxf(var,0.f)) + 1e-6f);
    float* so = scal + (size_t)(row0+row)*8;
    so[0]=p00; so[1]=p01; so[2]=p10; so[3]=p11; so[4]=mean; so[5]=inv;
  }
}

// ---------------- K2: 10 projections -> in-register combine -> out -----------
// p: 0:hl@hU't(w6) 1:hr@hU't(w6) 2:hl@hU'b(w7) 3:hr@hU'b(w7) 4:xh@hWu(w8)
//    5:xh@hWb(w9) 6:xh@lWu(w12) 7:xh@lWb(w13) 8:xw_lo@lU_t(w10) 9:xw_hi@lU_b(w11)
// Bsh slot b = wt_idx - 6: {0:hU't 1:hU'b 2:hWu 3:hWb 4:lU_t 5:lU_b 6:lWu 7:lWb}
// NT=64 (8 d-tiles), wave w owns cols [w*16, w*16+16).
template<int PRE>
__global__ __launch_bounds__(256,2) void k2(
    const float* __restrict__ hl, const float* __restrict__ hr,
    const float* __restrict__ xh, const float* __restrict__ xw,
    const unsigned short* __restrict__ hlb, const unsigned short* __restrict__ hrb,
    const unsigned short* __restrict__ xhb, const unsigned short* __restrict__ xwb,
    const unsigned short* __restrict__ wt,
    const float* __restrict__ sp, const float* __restrict__ tp,
    const float* __restrict__ hUb, const float* __restrict__ hWub, const float* __restrict__ hWbb,
    const float* __restrict__ lUb, const float* __restrict__ lWub, const float* __restrict__ lWbb,
    const float* __restrict__ scal, float* __restrict__ out)
{
  __shared__ __align__(16) unsigned short Ash[5*1024];   // 5 tiles 32x32
  __shared__ __align__(16) unsigned short Bsh[8*2048];   // 8 tiles 64x32
  __shared__ float scs[256];                             // 32 rows x 8 scalars
  const int tid = threadIdx.x, w = tid >> 6, lane = tid & 63;
  const int cq = lane & 15, cr = lane >> 4;
  const int row0 = blockIdx.x * 32;

  scs[tid] = scal[(size_t)row0*8 + tid];

  floatx4 acc[10][2];
  floatx4 zf; zf[0]=0.f; zf[1]=0.f; zf[2]=0.f; zf[3]=0.f;

#pragma unroll 1
  for (int dt = 0; dt < 8; dt++){
    const int d0 = dt * 64;
#pragma unroll
    for (int p=0;p<10;p++){ acc[p][0]=zf; acc[p][1]=zf; }

#pragma unroll 1
    for (int cc = 0; cc < 16; cc++){
      const int k0 = cc * 32;
      if (PRE){
#pragma unroll
        for (int j=0;j<3;j++){
          const int idx = j*256 + tid;
          if (idx < 640){
            const int a = idx>>7, wi = idx&127, r = wi>>2, kg = wi&3;
            const unsigned short* s;
            size_t off;
            if (a < 3){ s = (a==0) ? hlb : ((a==1) ? hrb : xhb);
                        off = (size_t)(row0+r)*512 + k0 + kg*8; }
            else      { s = xwb;
                        off = (size_t)(row0+r)*1024 + (a==4 ? 512 : 0) + k0 + kg*8; }
            gl_lds16(s + off, Ash + idx*8);
          }
        }
      } else {
#pragma unroll
        for (int a=0;a<5;a++){
          const int r = tid>>3, c4 = tid&7;
          const float* s = (a==0) ? hl : ((a==1) ? hr : ((a==2) ? xh : xw));
          const int stride = (a>=3) ? 1024 : 512;
          const int coff = (a==4) ? 512 : 0;
          const float4 v = *(const float4*)(s + (size_t)(row0+r)*stride + coff + k0 + c4*4);
          *(unsigned long long*)(Ash + a*1024 + r*32 + c4*4) = pack4(v);
        }
      }
#pragma unroll
      for (int j=0;j<8;j++){
        const int idx = j*256 + tid;
        const int m = idx>>8, wi = idx&255, r = wi>>2, kg = wi&3;
        gl_lds16(wt + (size_t)(6+m)*WMAT + (size_t)(d0+r)*512 + k0 + kg*8, Bsh + idx*8);
      }
      __syncthreads();
      shortx8 af[5][2], bf[8];
#pragma unroll
      for (int a=0;a<5;a++)
#pragma unroll
        for (int ms=0;ms<2;ms++)
          af[a][ms] = *(const shortx8*)(Ash + a*1024 + (ms*16+cq)*32 + cr*8);
#pragma unroll
      for (int m=0;m<8;m++)
        bf[m] = *(const shortx8*)(Bsh + m*2048 + (w*16 + cq)*32 + cr*8);
#pragma unroll
      for (int ms=0;ms<2;ms++){
        acc[0][ms] = MFMA16(af[0][ms], bf[0], acc[0][ms]);
        acc[1][ms] = MFMA16(af[1][ms], bf[0], acc[1][ms]);
        acc[2][ms] = MFMA16(af[0][ms], bf[1], acc[2][ms]);
        acc[3][ms] = MFMA16(af[1][ms], bf[1], acc[3][ms]);
        acc[4][ms] = MFMA16(af[2][ms], bf[2], acc[4][ms]);
        acc[5][ms] = MFMA16(af[2][ms], bf[3], acc[5][ms]);
        acc[6][ms] = MFMA16(af[2][ms], bf[6], acc[6][ms]);
        acc[7][ms] = MFMA16(af[2][ms], bf[7], acc[7][ms]);
        acc[8][ms] = MFMA16(af[3][ms], bf[4], acc[8][ms]);
        acc[9][ms] = MFMA16(af[4][ms], bf[5], acc[9][ms]);
      }
      __syncthreads();
    }
    // --------- in-register combine + store ---------
    const int col = d0 + w*16 + cq;
    const float spv = sp[col],  tpv = tp[col],  hub = hUb[col];
    const float hwub = hWub[col], hwbb = hWbb[col];
    const float lub = lUb[col], lwub = lWub[col], lwbb = lWbb[col];
#pragma unroll
    for (int ms=0;ms<2;ms++)
#pragma unroll
      for (int r=0;r<4;r++){
        const int row = ms*16 + cr*4 + r;
        const float p00 = scs[row*8+0], p01 = scs[row*8+1];
        const float p10 = scs[row*8+2], p11 = scs[row*8+3];
        const float mean = scs[row*8+4], inv = scs[row*8+5];
        const float a0 = 1.f+p00, a1 = p01, b0 = p10, b1 = 1.f+p11;
        const float attnU = a0*acc[0][ms][r] + a1*acc[1][ms][r]
                          + b0*acc[2][ms][r] + b1*acc[3][ms][r];
        const float xlnU = inv*(attnU - mean*spv) + tpv + hub;
        const float hid = xlnU*(acc[4][ms][r] + hwub) + (acc[5][ms][r] + hwbb);
        const float lf  = (acc[8][ms][r] + acc[9][ms][r] + lub)*(acc[6][ms][r] + lwub)
                        + (acc[7][ms][r] + lwbb);
        out[(size_t)(row0+row)*512 + col] = hid + lf;
      }
  }
}

// ---------------- launch -----------------------------------------------------
extern "C" void kernel_launch(void* const* d_in, const int* in_sizes, int n_in,
                              void* d_out, int out_size, void* d_ws, size_t ws_size,
                              hipStream_t stream)
{
  const float* hl    = (const float*)d_in[0];
  const float* hr    = (const float*)d_in[1];
  const float* xw    = (const float*)d_in[2];
  const float* xh    = (const float*)d_in[3];
  const float* qU_w  = (const float*)d_in[4];
  const float* qU_b  = (const float*)d_in[5];
  const float* qWu_w = (const float*)d_in[6];
  const float* qWu_b = (const float*)d_in[7];
  const float* qWb_w = (const float*)d_in[8];
  const float* qWb_b = (const float*)d_in[9];
  const float* kU_w  = (const float*)d_in[10];
  const float* kU_b  = (const float*)d_in[11];
  const float* kWu_w = (const float*)d_in[12];
  const float* kWu_b = (const float*)d_in[13];
  const float* kWb_w = (const float*)d_in[14];
  const float* kWb_b = (const float*)d_in[15];
  const float* alpha = (const float*)d_in[16];
  const float* beta  = (const float*)d_in[17];
  const float* hU_w  = (const float*)d_in[18];
  const float* hU_b  = (const float*)d_in[19];
  const float* hWu_w = (const float*)d_in[20];
  const float* hWu_b = (const float*)d_in[21];
  const float* hWb_w = (const float*)d_in[22];
  const float* hWb_b = (const float*)d_in[23];
  const float* lU_w  = (const float*)d_in[24];
  const float* lU_b  = (const float*)d_in[25];
  const float* lWu_w = (const float*)d_in[26];
  const float* lWu_b = (const float*)d_in[27];
  const float* lWb_w = (const float*)d_in[28];
  const float* lWb_b = (const float*)d_in[29];

  char* ws = (char*)d_ws;
  unsigned short* wt = (unsigned short*)ws;        // 14*512*512*2 = 7,340,032 B
  float* sp    = (float*)(ws + 7340032);           // 512 f32
  float* tp    = sp + 512;                         // 512 f32
  float* stats = (float*)(ws + 7344128);           // 32768*8 f32 = 1 MB
  float* scal  = (float*)(ws + 8392704);           // 32768*8 f32 = 1 MB
  unsigned short* hlb = (unsigned short*)(ws + 9441280);  // 32 MB
  unsigned short* hrb = hlb + 16777216;
  unsigned short* xhb = hrb + 16777216;
  unsigned short* xwb = xhb + 16777216;            // 64 MB
  const size_t NEED = 9441280ull + 3ull*33554432ull + 67108864ull; // 177,213,440
  const bool pre = (ws_size >= NEED);

  TrArgs ta;
  const float* wsrc[14] = {qU_w,kU_w,qWu_w,qWb_w,kWu_w,kWb_w,hU_w,hU_w,hWu_w,hWb_w,lU_w,lU_w,lWu_w,lWb_w};
  const int woff[14] = {0,0,0,0,0,0,0,512,0,0,0,512,0,0};
  const int wsc[14]  = {0,0,0,0,0,0,1,1,0,0,0,0,0,0};
  for (int i=0;i<14;i++){ ta.src[i]=wsrc[i]; ta.off[i]=woff[i]; ta.sc[i]=wsc[i]; }

  ktr<<<dim3(14*256), dim3(256), 0, stream>>>(ta, alpha, wt);
  kst<<<dim3(2),      dim3(256), 0, stream>>>(alpha, beta, hU_w, sp, tp);

  if (pre){
    kconv_stats<<<dim3(NROWS/4), dim3(256), 0, stream>>>(hl, hr, hlb, hrb, stats);
    kact<<<dim3(24576), dim3(256), 0, stream>>>(xh, xw, xhb, xwb);
    k1<1><<<dim3(NROWS/32), dim3(256), 0, stream>>>(hl, hr, xh, hlb, hrb, xhb, wt,
        qU_b, qWu_b, qWb_b, kU_b, kWu_b, kWb_b, stats, scal);
    k2<1><<<dim3(NROWS/32), dim3(256), 0, stream>>>(hl, hr, xh, xw, hlb, hrb, xhb, xwb, wt,
        sp, tp, hU_b, hWu_b, hWb_b, lU_b, lWu_b, lWb_b, scal, (float*)d_out);
  } else {
    kstats<<<dim3(NROWS/4), dim3(256), 0, stream>>>(hl, hr, stats);
    k1<0><<<dim3(NROWS/32), dim3(256), 0, stream>>>(hl, hr, xh, hlb, hrb, xhb, wt,
        qU_b, qWu_b, qWb_b, kU_b, kWu_b, kWb_b, stats, scal);
    k2<0><<<dim3(NROWS/32), dim3(256), 0, stream>>>(hl, hr, xh, xw, hlb, hrb, xhb, xwb, wt,
        sp, tp, hU_b, hWu_b, hWb_b, lU_b, lWu_b, lWb_b, scal, (float*)d_out);
  }
}